// Round 5
// baseline (873.875 us; speedup 1.0000x reference)
//
#include <hip/hip_runtime.h>
#include <cstdint>

// B=8, S=16, N=1024, F=16, H=128, E=32768, L=4, BN=8192
#define EPS 1e-5f

typedef unsigned short ushort_t;
typedef __bf16 bf16x8 __attribute__((ext_vector_type(8)));
typedef float f32x4 __attribute__((ext_vector_type(4)));

__device__ __forceinline__ float sigm(float x) { return 1.f / (1.f + expf(-x)); }
__device__ __forceinline__ unsigned short f2bf(float f) {
    unsigned int u = __builtin_bit_cast(unsigned int, f);
    return (unsigned short)((u + 0x7fffu + ((u >> 16) & 1u)) >> 16);
}
__device__ __forceinline__ float bf2f(unsigned short s) {
    unsigned int u = ((unsigned int)s) << 16;
    return __builtin_bit_cast(float, u);
}

// ---------------- edge attention
__global__ __launch_bounds__(256) void edge_att(const float* __restrict__ ef,
                                                const float* __restrict__ we1,
                                                const float* __restrict__ be1,
                                                const float* __restrict__ we2,
                                                const float* __restrict__ be2,
                                                const float* __restrict__ ewin,
                                                float* __restrict__ ew) {
    int e = blockIdx.x * blockDim.x + threadIdx.x;
    if (e >= 32768) return;
    float x = ef[e];
    float acc = 0.f;
    for (int h = 0; h < 128; ++h) {
        float v = fmaxf(x * we1[h] + be1[h], 0.f);
        acc += v * we2[h];
    }
    ew[e] = ewin[e] * sigm(acc + be2[0]);
}

__global__ __launch_bounds__(256) void deg_init(float* __restrict__ deg) {
    int i = blockIdx.x * blockDim.x + threadIdx.x;
    if (i < 8192) deg[i] = 1.0f;
}
__global__ __launch_bounds__(256) void deg_acc(const int* __restrict__ dst,
                                               const float* __restrict__ ew,
                                               float* __restrict__ deg) {
    int e = blockIdx.x * blockDim.x + threadIdx.x;
    if (e < 32768) atomicAdd(&deg[dst[e]], ew[e]);
}
__global__ __launch_bounds__(256) void make_dis(float* __restrict__ deg) {
    int i = blockIdx.x * blockDim.x + threadIdx.x;
    if (i < 8192) { float d = deg[i]; deg[i] = (d > 0.f) ? rsqrtf(d) : 0.f; }
}
__global__ __launch_bounds__(256) void scatterA(const int* __restrict__ src,
                                                const int* __restrict__ dst,
                                                const float* __restrict__ ew,
                                                const float* __restrict__ dis,
                                                float* __restrict__ A) {
    int e = blockIdx.x * blockDim.x + threadIdx.x;
    if (e >= 32768) return;
    int s = src[e], d = dst[e];
    atomicAdd(&A[d * 1024 + s], dis[s] * ew[e] * dis[d]);
}

// ---------------- converters
__global__ __launch_bounds__(256) void convF2B(const float* __restrict__ s,
                                               ushort_t* __restrict__ d, int n) {
    int i = blockIdx.x * blockDim.x + threadIdx.x;
    if (i < n) d[i] = f2bf(s[i]);
}
// gcnw [l][in][out] -> gcnwT [l][out][in] bf16
__global__ __launch_bounds__(256) void convW(const float* __restrict__ w,
                                             ushort_t* __restrict__ wt) {
    int i = blockIdx.x * blockDim.x + threadIdx.x;  // 4*128*128
    if (i >= 65536) return;
    int l = i >> 14, rem = i & 16383, in = rem >> 7, out = rem & 127;
    wt[l * 16384 + out * 128 + in] = f2bf(w[i]);
}
// LSTM weights -> gate-interleaved layout: col' = (h>>4)*64 + gate*16 + (h&15)
__global__ __launch_bounds__(256) void conv_lstm_w(const float* __restrict__ wih,
                                                   const float* __restrict__ whh,
                                                   ushort_t* __restrict__ wgi,
                                                   ushort_t* __restrict__ wgh) {
    int o = blockIdx.x * blockDim.x + threadIdx.x;  // 2*512*128
    if (o >= 131072) return;
    int l = o >> 16, rem = o & 65535, c = rem >> 7, k = rem & 127;
    int g = (c >> 4) & 3, h = (c >> 6) * 16 + (c & 15);
    int src = (l * 512 + g * 128 + h) * 128 + k;
    wgi[o] = f2bf(wih[src]);
    wgh[o] = f2bf(whh[src]);
}
__global__ __launch_bounds__(256) void conv_lstm_b(const float* __restrict__ bih,
                                                   const float* __restrict__ bhh,
                                                   float* __restrict__ bsg) {
    int o = blockIdx.x * blockDim.x + threadIdx.x;  // 1024
    if (o >= 1024) return;
    int l = o >> 9, c = o & 511;
    int g = (c >> 4) & 3, h = (c >> 6) * 16 + (c & 15);
    int src = l * 512 + g * 128 + h;
    bsg[o] = bih[src] + bhh[src];
}

// ---------------- input projection + LN + ReLU -> hcur_bf only
__global__ __launch_bounds__(128) void in_proj_ln(const float* __restrict__ x,
                                                  const float* __restrict__ w,
                                                  const float* __restrict__ bias,
                                                  const float* __restrict__ g,
                                                  const float* __restrict__ be,
                                                  ushort_t* __restrict__ hb) {
    int r = blockIdx.x;            // k*1024 + n, k in [0,23)
    int h = threadIdx.x;
    int k = r >> 10, n = r & 1023;
    __shared__ float xs[16];
    __shared__ float red[128];
    if (h < 16) xs[h] = x[(int64_t)r * 16 + h];
    __syncthreads();
    float acc = bias[h];
#pragma unroll
    for (int f = 0; f < 16; ++f) acc += xs[f] * w[f * 128 + h];
    red[h] = acc; __syncthreads();
    for (int off = 64; off; off >>= 1) { if (h < off) red[h] += red[h + off]; __syncthreads(); }
    float mu = red[0] * (1.f / 128.f); __syncthreads();
    float d = acc - mu; red[h] = d * d; __syncthreads();
    for (int off = 64; off; off >>= 1) { if (h < off) red[h] += red[h + off]; __syncthreads(); }
    float var = red[0] * (1.f / 128.f);
    float v = fmaxf(d * rsqrtf(var + EPS) * g[h] + be[h], 0.f);
    ushort_t vb = f2bf(v);
#pragma unroll
    for (int b = 0; b < 8; ++b) {
        int t = k - b;
        if (t >= 0 && t < 16)
            hb[((int64_t)t * 8192 + b * 1024 + n) * 128 + h] = vb;
    }
}

// ---------------- feature GEMM for rows<1024 per t, transposed output hwT[t][col][bn]
__global__ __launch_bounds__(256) void gemm_feat_t(const ushort_t* __restrict__ Hin,
                                                   const ushort_t* __restrict__ Wt,
                                                   ushort_t* __restrict__ hwT) {
    __shared__ __align__(16) char AsB[32768];
    __shared__ __align__(16) char BsB[32768];
    const int tid = threadIdx.x, lane = tid & 63, wid = tid >> 6;
    const int wr = wid >> 1, wc = wid & 1, q = lane >> 4, l15 = lane & 15;
    const int t = blockIdx.y;
    const int row0 = blockIdx.x * 128;
    const ushort_t* Ap = Hin + (int64_t)t * 1048576 + (int64_t)row0 * 128;
    f32x4 acc[4][4];
#pragma unroll
    for (int m = 0; m < 4; ++m)
#pragma unroll
        for (int n = 0; n < 4; ++n) acc[m][n] = f32x4{0.f, 0.f, 0.f, 0.f};
#pragma unroll
    for (int i = 0; i < 8; ++i) {
        int id = i * 256 + tid; int r = id >> 4, sg = id & 15;
        uint4 va = *(const uint4*)(Ap + r * 128 + sg * 8);
        *(uint4*)(AsB + r * 256 + ((sg * 16) ^ ((r & 7) << 4))) = va;
        uint4 vb = *(const uint4*)(Wt + r * 128 + sg * 8);
        *(uint4*)(BsB + r * 256 + ((sg * 16) ^ ((r & 7) << 4))) = vb;
    }
    __syncthreads();
#pragma unroll
    for (int kk = 0; kk < 4; ++kk) {
        bf16x8 af[4], bfr[4];
#pragma unroll
        for (int m = 0; m < 4; ++m) {
            int row = wr * 64 + m * 16 + l15;
            af[m] = __builtin_bit_cast(bf16x8,
                *(const uint4*)(AsB + row * 256 + ((kk * 64 + q * 16) ^ ((row & 7) << 4))));
        }
#pragma unroll
        for (int n = 0; n < 4; ++n) {
            int col = wc * 64 + n * 16 + l15;
            bfr[n] = __builtin_bit_cast(bf16x8,
                *(const uint4*)(BsB + col * 256 + ((kk * 64 + q * 16) ^ ((col & 7) << 4))));
        }
#pragma unroll
        for (int m = 0; m < 4; ++m)
#pragma unroll
            for (int n = 0; n < 4; ++n)
                acc[m][n] = __builtin_amdgcn_mfma_f32_16x16x32_bf16(af[m], bfr[n], acc[m][n], 0, 0, 0);
    }
#pragma unroll
    for (int m = 0; m < 4; ++m) {
        int bn = row0 + wr * 64 + m * 16 + q * 4;
#pragma unroll
        for (int n = 0; n < 4; ++n) {
            int col = wc * 64 + n * 16 + l15;
            ushort4 u;
            u.x = f2bf(acc[m][n][0]); u.y = f2bf(acc[m][n][1]);
            u.z = f2bf(acc[m][n][2]); u.w = f2bf(acc[m][n][3]);
            *(ushort4*)(hwT + ((int64_t)t * 128 + col) * 1024 + bn) = u;
        }
    }
}

// ---------------- adjacency GEMM: Apart[t] = Adense_bf @ hw[t]  (B as hwT [col][bn])
__global__ __launch_bounds__(256) void gemm_adj(const ushort_t* __restrict__ Abf,
                                                const ushort_t* __restrict__ hwT,
                                                float* __restrict__ Apart) {
    __shared__ __align__(16) char AsB[8192];    // 64 rows x 64k
    __shared__ __align__(16) char BsB[16384];   // 128 cols x 64k
    const int tid = threadIdx.x, lane = tid & 63, wid = tid >> 6;
    const int wr = wid >> 1, wc = wid & 1, q = lane >> 4, l15 = lane & 15;
    const int row0 = blockIdx.x * 64;
    const int t = blockIdx.z;
    const ushort_t* Bp = hwT + (int64_t)t * 131072;
    f32x4 acc[2][4];
#pragma unroll
    for (int m = 0; m < 2; ++m)
#pragma unroll
        for (int n = 0; n < 4; ++n) acc[m][n] = f32x4{0.f, 0.f, 0.f, 0.f};
    for (int k0 = 0; k0 < 1024; k0 += 64) {
        __syncthreads();
#pragma unroll
        for (int i = 0; i < 2; ++i) {
            int id = i * 256 + tid; int r = id >> 3, sg = id & 7;
            uint4 v = *(const uint4*)(Abf + (int64_t)(row0 + r) * 1024 + k0 + sg * 8);
            *(uint4*)(AsB + r * 128 + ((sg * 16) ^ ((r & 7) << 4))) = v;
        }
#pragma unroll
        for (int i = 0; i < 4; ++i) {
            int id = i * 256 + tid; int r = id >> 3, sg = id & 7;
            uint4 v = *(const uint4*)(Bp + (int64_t)r * 1024 + k0 + sg * 8);
            *(uint4*)(BsB + r * 128 + ((sg * 16) ^ ((r & 7) << 4))) = v;
        }
        __syncthreads();
#pragma unroll
        for (int kk = 0; kk < 2; ++kk) {
            bf16x8 af[2], bfr[4];
#pragma unroll
            for (int m = 0; m < 2; ++m) {
                int row = wr * 32 + m * 16 + l15;
                af[m] = __builtin_bit_cast(bf16x8,
                    *(const uint4*)(AsB + row * 128 + ((kk * 64 + q * 16) ^ ((row & 7) << 4))));
            }
#pragma unroll
            for (int n = 0; n < 4; ++n) {
                int col = wc * 64 + n * 16 + l15;
                bfr[n] = __builtin_bit_cast(bf16x8,
                    *(const uint4*)(BsB + col * 128 + ((kk * 64 + q * 16) ^ ((col & 7) << 4))));
            }
#pragma unroll
            for (int m = 0; m < 2; ++m)
#pragma unroll
                for (int n = 0; n < 4; ++n)
                    acc[m][n] = __builtin_amdgcn_mfma_f32_16x16x32_bf16(af[m], bfr[n], acc[m][n], 0, 0, 0);
        }
    }
#pragma unroll
    for (int m = 0; m < 2; ++m) {
        int rb = row0 + wr * 32 + m * 16 + q * 4;
#pragma unroll
        for (int n = 0; n < 4; ++n) {
            int c = wc * 64 + n * 16 + l15;
#pragma unroll
            for (int e = 0; e < 4; ++e)
                Apart[((int64_t)t * 1024 + rb + e) * 128 + c] = acc[m][n][e];
        }
    }
}

// ---------------- fused GCN layer: hw = Hin@W; h = relu((sl*hw + Apart + b)*scale + bnb) + Hin
// Output staged via LDS (BsB reused) -> coalesced uint4 stores.
__global__ __launch_bounds__(256) void gcn_fused(const ushort_t* __restrict__ Hin,
                                                 const ushort_t* __restrict__ Wt,
                                                 const float* __restrict__ Apart,
                                                 const float* __restrict__ dis,
                                                 const float* __restrict__ gcnb,
                                                 const float* __restrict__ bng,
                                                 const float* __restrict__ bnb,
                                                 ushort_t* __restrict__ Hout) {
    __shared__ __align__(16) char AsB[32768];
    __shared__ __align__(16) char BsB[32768];
    const int tid = threadIdx.x, lane = tid & 63, wid = tid >> 6;
    const int wr = wid >> 1, wc = wid & 1, q = lane >> 4, l15 = lane & 15;
    const int64_t row0 = (int64_t)blockIdx.x * 128;
    const ushort_t* Ap = Hin + row0 * 128;
    f32x4 acc[4][4];
#pragma unroll
    for (int m = 0; m < 4; ++m)
#pragma unroll
        for (int n = 0; n < 4; ++n) acc[m][n] = f32x4{0.f, 0.f, 0.f, 0.f};
#pragma unroll
    for (int i = 0; i < 8; ++i) {
        int id = i * 256 + tid; int r = id >> 4, sg = id & 15;
        uint4 va = *(const uint4*)(Ap + r * 128 + sg * 8);
        *(uint4*)(AsB + r * 256 + ((sg * 16) ^ ((r & 7) << 4))) = va;
        uint4 vb = *(const uint4*)(Wt + r * 128 + sg * 8);
        *(uint4*)(BsB + r * 256 + ((sg * 16) ^ ((r & 7) << 4))) = vb;
    }
    __syncthreads();
#pragma unroll
    for (int kk = 0; kk < 4; ++kk) {
        bf16x8 af[4], bfr[4];
#pragma unroll
        for (int m = 0; m < 4; ++m) {
            int row = wr * 64 + m * 16 + l15;
            af[m] = __builtin_bit_cast(bf16x8,
                *(const uint4*)(AsB + row * 256 + ((kk * 64 + q * 16) ^ ((row & 7) << 4))));
        }
#pragma unroll
        for (int n = 0; n < 4; ++n) {
            int col = wc * 64 + n * 16 + l15;
            bfr[n] = __builtin_bit_cast(bf16x8,
                *(const uint4*)(BsB + col * 256 + ((kk * 64 + q * 16) ^ ((col & 7) << 4))));
        }
#pragma unroll
        for (int m = 0; m < 4; ++m)
#pragma unroll
            for (int n = 0; n < 4; ++n)
                acc[m][n] = __builtin_amdgcn_mfma_f32_16x16x32_bf16(af[m], bfr[n], acc[m][n], 0, 0, 0);
    }
    __syncthreads();   // all BsB (weight) frag reads done; BsB becomes out-tile
    const int bn0 = (int)(row0 & 8191);
    const int t = (int)(row0 >> 13);
    const bool hasA = bn0 < 1024;
    const float rs = rsqrtf(1.f + EPS);
#pragma unroll
    for (int n = 0; n < 4; ++n) {
        int col = wc * 64 + n * 16 + l15;
        float gb = gcnb[col], sc = bng[col] * rs, bb = bnb[col];
        int seg16 = (col >> 3) * 16, wb = (col & 7) * 2;
#pragma unroll
        for (int m = 0; m < 4; ++m) {
            int rl0 = wr * 64 + m * 16 + q * 4;
#pragma unroll
            for (int e = 0; e < 4; ++e) {
                int rl = rl0 + e;
                int bn = bn0 + rl;
                float sl = dis[bn]; sl *= sl;
                float mv = sl * acc[m][n][e] + gb;
                if (hasA) mv += Apart[((int64_t)t * 1024 + bn) * 128 + col];
                ushort_t rbv = *(const ushort_t*)(AsB + rl * 256 + (seg16 ^ ((rl & 7) << 4)) + wb);
                float v = fmaxf(mv * sc + bb, 0.f) + bf2f(rbv);
                *(ushort_t*)(BsB + rl * 256 + (seg16 ^ ((rl & 7) << 4)) + wb) = f2bf(v);
            }
        }
    }
    __syncthreads();
#pragma unroll
    for (int i = 0; i < 8; ++i) {
        int id = i * 256 + tid; int r = id >> 4, sg = id & 15;
        uint4 v = *(const uint4*)(BsB + r * 256 + ((sg * 16) ^ ((r & 7) << 4)));
        *(uint4*)(Hout + (row0 + r) * 128 + sg * 8) = v;
    }
}

// ---------------- persistent 2-layer LSTM, single dispatch.
// 128 blocks x 512 threads (8 waves). Block owns 64 rows; rows are LAYER-LOCAL
// across both layers, so the whole recurrence runs in one block: x staged to LDS,
// h1/h2 in LDS (bf16), c1/c2 in VGPRs. Weights gate-interleaved, streamed from L2
// directly into B-fragments (same addresses every step). Wave w owns gate-cols'
// [w*64,w*64+64) = hidden [w*16,w*16+16); n-frag = gate (i,f,g,o).
__device__ __forceinline__ void lstm_pass(
    const char* __restrict__ Axs, const char* __restrict__ Ahs, char* __restrict__ Hout,
    const ushort_t* __restrict__ Wi, const ushort_t* __restrict__ Wh,
    float c[4][4], float bi, float bf, float bg, float bo,
    int w, int q, int l15) {
    f32x4 acc[4][4];
#pragma unroll
    for (int m = 0; m < 4; ++m)
#pragma unroll
        for (int n = 0; n < 4; ++n) acc[m][n] = f32x4{0.f, 0.f, 0.f, 0.f};
#pragma unroll
    for (int kk = 0; kk < 4; ++kk) {
        bf16x8 ax[4], ah[4];
#pragma unroll
        for (int m = 0; m < 4; ++m) {
            int row = m * 16 + l15;
            int off = row * 256 + ((kk * 64 + q * 16) ^ ((row & 7) << 4));
            ax[m] = __builtin_bit_cast(bf16x8, *(const uint4*)(Axs + off));
            ah[m] = __builtin_bit_cast(bf16x8, *(const uint4*)(Ahs + off));
        }
#pragma unroll
        for (int n = 0; n < 4; ++n) {
            int col = w * 64 + n * 16 + l15;
            bf16x8 bwi = __builtin_bit_cast(bf16x8, *(const uint4*)(Wi + col * 128 + kk * 32 + q * 8));
            bf16x8 bwh = __builtin_bit_cast(bf16x8, *(const uint4*)(Wh + col * 128 + kk * 32 + q * 8));
#pragma unroll
            for (int m = 0; m < 4; ++m) {
                acc[m][n] = __builtin_amdgcn_mfma_f32_16x16x32_bf16(ax[m], bwi, acc[m][n], 0, 0, 0);
                acc[m][n] = __builtin_amdgcn_mfma_f32_16x16x32_bf16(ah[m], bwh, acc[m][n], 0, 0, 0);
            }
        }
    }
    __syncthreads();   // all reads of Ahs/Axs done before Hout (may alias) is written
    const int k = w * 16 + l15;
    const int kb = ((k >> 3) * 16) + (k & 7) * 2;
#pragma unroll
    for (int m = 0; m < 4; ++m) {
#pragma unroll
        for (int e = 0; e < 4; ++e) {
            float ig = sigm(acc[m][0][e] + bi);
            float fg = sigm(acc[m][1][e] + bf);
            float gg = tanhf(acc[m][2][e] + bg);
            float og = sigm(acc[m][3][e] + bo);
            float cn = fg * c[m][e] + ig * gg;
            c[m][e] = cn;
            float hn = og * tanhf(cn);
            int row = m * 16 + q * 4 + e;
            int byte = row * 256 + ((((k >> 3) * 16) ^ ((row & 7) << 4)) | ((k & 7) * 2));
            *(ushort_t*)(Hout + byte) = f2bf(hn);
        }
    }
    (void)kb;
    __syncthreads();   // new h visible to all waves
}

__global__ __launch_bounds__(512, 1) void lstm_all(
    const ushort_t* __restrict__ X,        // [16][8192][128]
    const ushort_t* __restrict__ Wi1, const ushort_t* __restrict__ Wh1,
    const ushort_t* __restrict__ Wi2, const ushort_t* __restrict__ Wh2,
    const float* __restrict__ bs1, const float* __restrict__ bs2,
    ushort_t* __restrict__ h2out) {        // [8192][128]
    __shared__ __align__(16) char Xs[16384];
    __shared__ __align__(16) char H1[16384];
    __shared__ __align__(16) char H2[16384];
    const int tid = threadIdx.x, lane = tid & 63, w = tid >> 6;
    const int q = lane >> 4, l15 = lane & 15;
    const int row0 = blockIdx.x * 64;
#pragma unroll
    for (int i = 0; i < 2; ++i) {
        int id = i * 512 + tid;
        *(uint4*)(H1 + id * 16) = uint4{0, 0, 0, 0};
        *(uint4*)(H2 + id * 16) = uint4{0, 0, 0, 0};
    }
    float c1[4][4] = {}, c2[4][4] = {};
    const int cb = w * 64 + l15;
    const float bi1 = bs1[cb], bf1 = bs1[cb + 16], bg1 = bs1[cb + 32], bo1 = bs1[cb + 48];
    const float bi2 = bs2[cb], bf2 = bs2[cb + 16], bg2 = bs2[cb + 32], bo2 = bs2[cb + 48];
    __syncthreads();
    for (int t = 0; t < 16; ++t) {
        // stage X[t] rows -> Xs (coalesced, swizzled)
#pragma unroll
        for (int i = 0; i < 2; ++i) {
            int id = i * 512 + tid; int r = id >> 4, sg = id & 15;
            uint4 v = *(const uint4*)(X + ((int64_t)t * 8192 + row0 + r) * 128 + sg * 8);
            *(uint4*)(Xs + r * 256 + ((sg * 16) ^ ((r & 7) << 4))) = v;
        }
        __syncthreads();
        lstm_pass(Xs, H1, H1, Wi1, Wh1, c1, bi1, bf1, bg1, bo1, w, q, l15);
        lstm_pass(H1, H2, H2, Wi2, Wh2, c2, bi2, bf2, bg2, bo2, w, q, l15);
    }
#pragma unroll
    for (int i = 0; i < 2; ++i) {
        int id = i * 512 + tid; int r = id >> 4, sg = id & 15;
        uint4 v = *(const uint4*)(H2 + r * 256 + ((sg * 16) ^ ((r & 7) << 4)));
        *(uint4*)(h2out + (int64_t)(row0 + r) * 128 + sg * 8) = v;
    }
}

// ---------------- output head
__global__ __launch_bounds__(64) void out_head(const ushort_t* __restrict__ y,
                                               const float* __restrict__ w1,
                                               const float* __restrict__ b1,
                                               const float* __restrict__ g,
                                               const float* __restrict__ be,
                                               const float* __restrict__ w2,
                                               const float* __restrict__ b2,
                                               float* __restrict__ out) {
    int r = blockIdx.x;  // 0..8191
    int j = threadIdx.x; // 0..63
    const ushort_t* yr = y + (int64_t)r * 128;
    float acc = b1[j];
    for (int k = 0; k < 128; ++k) acc += bf2f(yr[k]) * w1[k * 64 + j];
    float s = acc;
    for (int off = 32; off; off >>= 1) s += __shfl_xor(s, off, 64);
    float mu = s * (1.f / 64.f);
    float d = acc - mu;
    float vs = d * d;
    for (int off = 32; off; off >>= 1) vs += __shfl_xor(vs, off, 64);
    float var = vs * (1.f / 64.f);
    float z = fmaxf(d * rsqrtf(var + EPS) * g[j] + be[j], 0.f);
    float p = z * w2[j];
    for (int off = 32; off; off >>= 1) p += __shfl_xor(p, off, 64);
    if (j == 0) out[r] = p + b2[0];
}

extern "C" void kernel_launch(void* const* d_in, const int* in_sizes, int n_in,
                              void* d_out, int out_size, void* d_ws, size_t ws_size,
                              hipStream_t stream) {
    const float* x    = (const float*)d_in[0];
    const int*   eidx = (const int*)d_in[1];
    const float* ewt  = (const float*)d_in[2];
    const float* efeat= (const float*)d_in[3];
    const float* w_in = (const float*)d_in[4];
    const float* b_in = (const float*)d_in[5];
    const float* lng  = (const float*)d_in[6];
    const float* lnb  = (const float*)d_in[7];
    const float* we1  = (const float*)d_in[8];
    const float* be1  = (const float*)d_in[9];
    const float* we2  = (const float*)d_in[10];
    const float* be2  = (const float*)d_in[11];
    const float* gcnw = (const float*)d_in[12];
    const float* gcnb = (const float*)d_in[13];
    const float* bng  = (const float*)d_in[14];
    const float* bnb  = (const float*)d_in[15];
    const float* wih  = (const float*)d_in[16];
    const float* whh  = (const float*)d_in[17];
    const float* bih  = (const float*)d_in[18];
    const float* bhh  = (const float*)d_in[19];
    const float* wo1  = (const float*)d_in[20];
    const float* bo1  = (const float*)d_in[21];
    const float* lnog = (const float*)d_in[22];
    const float* lnob = (const float*)d_in[23];
    const float* wo2  = (const float*)d_in[24];
    const float* bo2  = (const float*)d_in[25];
    float* out = (float*)d_out;

    // ---- workspace layout (~53MB)
    char* W = (char*)d_ws;
    ushort_t* hcur_bf   = (ushort_t*)(W);                        // 32MB [16][8192][128]
    ushort_t* hwT       = (ushort_t*)(W + (32ll << 20));         // 4MB  [16][128][1024]
    float*    Apart     = (float*)(W + (36ll << 20));            // 8MB  [16][1024][128]
    float*    Adense    = (float*)(W + (44ll << 20));            // 4MB
    ushort_t* Adense_bf = (ushort_t*)(W + (48ll << 20));         // 2MB
    ushort_t* h2out     = (ushort_t*)(W + (50ll << 20));         // 2MB [8192][128]
    float*    ew        = (float*)(W + (52ll << 20));            // 128KB
    float*    dis       = (float*)(W + (52ll << 20) + 0x20000);  // 32KB
    float*    bsg       = (float*)(W + (52ll << 20) + 0x28000);  // 4KB [2][512]
    ushort_t* gcnwT     = (ushort_t*)(W + (52ll << 20) + 0x30000); // 128KB
    ushort_t* wgi       = (ushort_t*)(W + (52ll << 20) + 0x50000); // 256KB [2][512][128]
    ushort_t* wgh       = (ushort_t*)(W + (52ll << 20) + 0x90000); // 256KB

    const int* srcI = eidx;
    const int* dstI = eidx + 32768;

    // graph preprocessing
    edge_att<<<128, 256, 0, stream>>>(efeat, we1, be1, we2, be2, ewt, ew);
    deg_init<<<32, 256, 0, stream>>>(dis);
    deg_acc<<<128, 256, 0, stream>>>(dstI, ew, dis);
    make_dis<<<32, 256, 0, stream>>>(dis);
    hipMemsetAsync(Adense, 0, 1048576 * sizeof(float), stream);
    scatterA<<<128, 256, 0, stream>>>(srcI, dstI, ew, dis, Adense);
    convF2B<<<4096, 256, 0, stream>>>(Adense, Adense_bf, 1048576);

    // weight conversions
    convW<<<256, 256, 0, stream>>>(gcnw, gcnwT);
    conv_lstm_w<<<512, 256, 0, stream>>>(wih, whh, wgi, wgh);
    conv_lstm_b<<<4, 256, 0, stream>>>(bih, bhh, bsg);

    // input projection (bf16 only)
    in_proj_ln<<<23552, 128, 0, stream>>>(x, w_in, b_in, lng, lnb, hcur_bf);

    // GCN layers
    for (int l = 0; l < 4; ++l) {
        gemm_feat_t<<<dim3(8, 16, 1), 256, 0, stream>>>(hcur_bf, gcnwT + l * 16384, hwT);
        gemm_adj<<<dim3(16, 1, 16), 256, 0, stream>>>(Adense_bf, hwT, Apart);
        gcn_fused<<<1024, 256, 0, stream>>>(hcur_bf, gcnwT + l * 16384, Apart, dis,
                                            gcnb + l * 128, bng + l * 128, bnb + l * 128,
                                            hcur_bf);
    }

    // LSTM: one persistent dispatch, both layers, c-state in registers
    lstm_all<<<128, 512, 0, stream>>>(hcur_bf, wgi, wgh, wgi + 65536, wgh + 65536,
                                      bsg, bsg + 512, h2out);

    // output head
    out_head<<<8192, 64, 0, stream>>>(h2out, wo1, bo1, lnog, lnob, wo2, bo2, out);
}

// Round 6
// 423.777 us; speedup vs baseline: 2.0621x; 2.0621x over previous
//
#include <hip/hip_runtime.h>
#include <cstdint>

// B=8, S=16, N=1024, F=16, H=128, E=32768, L=4, BN=8192
#define EPS 1e-5f

typedef unsigned short ushort_t;
typedef __bf16 bf16x8 __attribute__((ext_vector_type(8)));
typedef float f32x4 __attribute__((ext_vector_type(4)));

__device__ __forceinline__ float sigm(float x) { return 1.f / (1.f + expf(-x)); }
__device__ __forceinline__ unsigned short f2bf(float f) {
    unsigned int u = __builtin_bit_cast(unsigned int, f);
    return (unsigned short)((u + 0x7fffu + ((u >> 16) & 1u)) >> 16);
}
__device__ __forceinline__ float bf2f(unsigned short s) {
    unsigned int u = ((unsigned int)s) << 16;
    return __builtin_bit_cast(float, u);
}
// fast transcendentals for the LSTM cell (v_exp_f32 / v_rcp_f32)
__device__ __forceinline__ float sigm_fast(float x) {
    float t = __builtin_amdgcn_exp2f(-1.44269504f * x);
    return __builtin_amdgcn_rcpf(1.f + t);
}
__device__ __forceinline__ float tanh_fast(float x) {
    float xc = fminf(fmaxf(x, -15.f), 15.f);
    float t = __builtin_amdgcn_exp2f(-2.88539008f * xc);
    return (1.f - t) * __builtin_amdgcn_rcpf(1.f + t);
}

// ---------------- edge attention
__global__ __launch_bounds__(256) void edge_att(const float* __restrict__ ef,
                                                const float* __restrict__ we1,
                                                const float* __restrict__ be1,
                                                const float* __restrict__ we2,
                                                const float* __restrict__ be2,
                                                const float* __restrict__ ewin,
                                                float* __restrict__ ew) {
    int e = blockIdx.x * blockDim.x + threadIdx.x;
    if (e >= 32768) return;
    float x = ef[e];
    float acc = 0.f;
    for (int h = 0; h < 128; ++h) {
        float v = fmaxf(x * we1[h] + be1[h], 0.f);
        acc += v * we2[h];
    }
    ew[e] = ewin[e] * sigm(acc + be2[0]);
}

__global__ __launch_bounds__(256) void deg_init(float* __restrict__ deg) {
    int i = blockIdx.x * blockDim.x + threadIdx.x;
    if (i < 8192) deg[i] = 1.0f;
}
__global__ __launch_bounds__(256) void deg_acc(const int* __restrict__ dst,
                                               const float* __restrict__ ew,
                                               float* __restrict__ deg) {
    int e = blockIdx.x * blockDim.x + threadIdx.x;
    if (e < 32768) atomicAdd(&deg[dst[e]], ew[e]);
}
__global__ __launch_bounds__(256) void make_dis(float* __restrict__ deg) {
    int i = blockIdx.x * blockDim.x + threadIdx.x;
    if (i < 8192) { float d = deg[i]; deg[i] = (d > 0.f) ? rsqrtf(d) : 0.f; }
}
__global__ __launch_bounds__(256) void scatterA(const int* __restrict__ src,
                                                const int* __restrict__ dst,
                                                const float* __restrict__ ew,
                                                const float* __restrict__ dis,
                                                float* __restrict__ A) {
    int e = blockIdx.x * blockDim.x + threadIdx.x;
    if (e >= 32768) return;
    int s = src[e], d = dst[e];
    atomicAdd(&A[d * 1024 + s], dis[s] * ew[e] * dis[d]);
}

// ---------------- converters
__global__ __launch_bounds__(256) void convF2B(const float* __restrict__ s,
                                               ushort_t* __restrict__ d, int n) {
    int i = blockIdx.x * blockDim.x + threadIdx.x;
    if (i < n) d[i] = f2bf(s[i]);
}
// gcnw [l][in][out] -> gcnwT [l][out][in] bf16
__global__ __launch_bounds__(256) void convW(const float* __restrict__ w,
                                             ushort_t* __restrict__ wt) {
    int i = blockIdx.x * blockDim.x + threadIdx.x;  // 4*128*128
    if (i >= 65536) return;
    int l = i >> 14, rem = i & 16383, in = rem >> 7, out = rem & 127;
    wt[l * 16384 + out * 128 + in] = f2bf(w[i]);
}
// LSTM weights -> gate-interleaved layout: col' = (h>>4)*64 + gate*16 + (h&15)
__global__ __launch_bounds__(256) void conv_lstm_w(const float* __restrict__ wih,
                                                   const float* __restrict__ whh,
                                                   ushort_t* __restrict__ wgi,
                                                   ushort_t* __restrict__ wgh) {
    int o = blockIdx.x * blockDim.x + threadIdx.x;  // 2*512*128
    if (o >= 131072) return;
    int l = o >> 16, rem = o & 65535, c = rem >> 7, k = rem & 127;
    int g = (c >> 4) & 3, h = (c >> 6) * 16 + (c & 15);
    int src = (l * 512 + g * 128 + h) * 128 + k;
    wgi[o] = f2bf(wih[src]);
    wgh[o] = f2bf(whh[src]);
}
__global__ __launch_bounds__(256) void conv_lstm_b(const float* __restrict__ bih,
                                                   const float* __restrict__ bhh,
                                                   float* __restrict__ bsg) {
    int o = blockIdx.x * blockDim.x + threadIdx.x;  // 1024
    if (o >= 1024) return;
    int l = o >> 9, c = o & 511;
    int g = (c >> 4) & 3, h = (c >> 6) * 16 + (c & 15);
    int src = l * 512 + g * 128 + h;
    bsg[o] = bih[src] + bhh[src];
}

// ---------------- input projection + LN + ReLU -> hcur_bf only
__global__ __launch_bounds__(128) void in_proj_ln(const float* __restrict__ x,
                                                  const float* __restrict__ w,
                                                  const float* __restrict__ bias,
                                                  const float* __restrict__ g,
                                                  const float* __restrict__ be,
                                                  ushort_t* __restrict__ hb) {
    int r = blockIdx.x;            // k*1024 + n, k in [0,23)
    int h = threadIdx.x;
    int k = r >> 10, n = r & 1023;
    __shared__ float xs[16];
    __shared__ float red[128];
    if (h < 16) xs[h] = x[(int64_t)r * 16 + h];
    __syncthreads();
    float acc = bias[h];
#pragma unroll
    for (int f = 0; f < 16; ++f) acc += xs[f] * w[f * 128 + h];
    red[h] = acc; __syncthreads();
    for (int off = 64; off; off >>= 1) { if (h < off) red[h] += red[h + off]; __syncthreads(); }
    float mu = red[0] * (1.f / 128.f); __syncthreads();
    float d = acc - mu; red[h] = d * d; __syncthreads();
    for (int off = 64; off; off >>= 1) { if (h < off) red[h] += red[h + off]; __syncthreads(); }
    float var = red[0] * (1.f / 128.f);
    float v = fmaxf(d * rsqrtf(var + EPS) * g[h] + be[h], 0.f);
    ushort_t vb = f2bf(v);
#pragma unroll
    for (int b = 0; b < 8; ++b) {
        int t = k - b;
        if (t >= 0 && t < 16)
            hb[((int64_t)t * 8192 + b * 1024 + n) * 128 + h] = vb;
    }
}

// ---------------- feature GEMM for rows<1024 per t, transposed output hwT[t][col][bn]
__global__ __launch_bounds__(256) void gemm_feat_t(const ushort_t* __restrict__ Hin,
                                                   const ushort_t* __restrict__ Wt,
                                                   ushort_t* __restrict__ hwT) {
    __shared__ __align__(16) char AsB[32768];
    __shared__ __align__(16) char BsB[32768];
    const int tid = threadIdx.x, lane = tid & 63, wid = tid >> 6;
    const int wr = wid >> 1, wc = wid & 1, q = lane >> 4, l15 = lane & 15;
    const int t = blockIdx.y;
    const int row0 = blockIdx.x * 128;
    const ushort_t* Ap = Hin + (int64_t)t * 1048576 + (int64_t)row0 * 128;
    f32x4 acc[4][4];
#pragma unroll
    for (int m = 0; m < 4; ++m)
#pragma unroll
        for (int n = 0; n < 4; ++n) acc[m][n] = f32x4{0.f, 0.f, 0.f, 0.f};
#pragma unroll
    for (int i = 0; i < 8; ++i) {
        int id = i * 256 + tid; int r = id >> 4, sg = id & 15;
        uint4 va = *(const uint4*)(Ap + r * 128 + sg * 8);
        *(uint4*)(AsB + r * 256 + ((sg * 16) ^ ((r & 7) << 4))) = va;
        uint4 vb = *(const uint4*)(Wt + r * 128 + sg * 8);
        *(uint4*)(BsB + r * 256 + ((sg * 16) ^ ((r & 7) << 4))) = vb;
    }
    __syncthreads();
#pragma unroll
    for (int kk = 0; kk < 4; ++kk) {
        bf16x8 af[4], bfr[4];
#pragma unroll
        for (int m = 0; m < 4; ++m) {
            int row = wr * 64 + m * 16 + l15;
            af[m] = __builtin_bit_cast(bf16x8,
                *(const uint4*)(AsB + row * 256 + ((kk * 64 + q * 16) ^ ((row & 7) << 4))));
        }
#pragma unroll
        for (int n = 0; n < 4; ++n) {
            int col = wc * 64 + n * 16 + l15;
            bfr[n] = __builtin_bit_cast(bf16x8,
                *(const uint4*)(BsB + col * 256 + ((kk * 64 + q * 16) ^ ((col & 7) << 4))));
        }
#pragma unroll
        for (int m = 0; m < 4; ++m)
#pragma unroll
            for (int n = 0; n < 4; ++n)
                acc[m][n] = __builtin_amdgcn_mfma_f32_16x16x32_bf16(af[m], bfr[n], acc[m][n], 0, 0, 0);
    }
#pragma unroll
    for (int m = 0; m < 4; ++m) {
        int bn = row0 + wr * 64 + m * 16 + q * 4;
#pragma unroll
        for (int n = 0; n < 4; ++n) {
            int col = wc * 64 + n * 16 + l15;
            ushort4 u;
            u.x = f2bf(acc[m][n][0]); u.y = f2bf(acc[m][n][1]);
            u.z = f2bf(acc[m][n][2]); u.w = f2bf(acc[m][n][3]);
            *(ushort4*)(hwT + ((int64_t)t * 128 + col) * 1024 + bn) = u;
        }
    }
}

// ---------------- adjacency GEMM: Apart[t] = Adense_bf @ hw[t]  (B as hwT [col][bn])
__global__ __launch_bounds__(256) void gemm_adj(const ushort_t* __restrict__ Abf,
                                                const ushort_t* __restrict__ hwT,
                                                float* __restrict__ Apart) {
    __shared__ __align__(16) char AsB[8192];    // 64 rows x 64k
    __shared__ __align__(16) char BsB[16384];   // 128 cols x 64k
    const int tid = threadIdx.x, lane = tid & 63, wid = tid >> 6;
    const int wr = wid >> 1, wc = wid & 1, q = lane >> 4, l15 = lane & 15;
    const int row0 = blockIdx.x * 64;
    const int t = blockIdx.z;
    const ushort_t* Bp = hwT + (int64_t)t * 131072;
    f32x4 acc[2][4];
#pragma unroll
    for (int m = 0; m < 2; ++m)
#pragma unroll
        for (int n = 0; n < 4; ++n) acc[m][n] = f32x4{0.f, 0.f, 0.f, 0.f};
    for (int k0 = 0; k0 < 1024; k0 += 64) {
        __syncthreads();
#pragma unroll
        for (int i = 0; i < 2; ++i) {
            int id = i * 256 + tid; int r = id >> 3, sg = id & 7;
            uint4 v = *(const uint4*)(Abf + (int64_t)(row0 + r) * 1024 + k0 + sg * 8);
            *(uint4*)(AsB + r * 128 + ((sg * 16) ^ ((r & 7) << 4))) = v;
        }
#pragma unroll
        for (int i = 0; i < 4; ++i) {
            int id = i * 256 + tid; int r = id >> 3, sg = id & 7;
            uint4 v = *(const uint4*)(Bp + (int64_t)r * 1024 + k0 + sg * 8);
            *(uint4*)(BsB + r * 128 + ((sg * 16) ^ ((r & 7) << 4))) = v;
        }
        __syncthreads();
#pragma unroll
        for (int kk = 0; kk < 2; ++kk) {
            bf16x8 af[2], bfr[4];
#pragma unroll
            for (int m = 0; m < 2; ++m) {
                int row = wr * 32 + m * 16 + l15;
                af[m] = __builtin_bit_cast(bf16x8,
                    *(const uint4*)(AsB + row * 128 + ((kk * 64 + q * 16) ^ ((row & 7) << 4))));
            }
#pragma unroll
            for (int n = 0; n < 4; ++n) {
                int col = wc * 64 + n * 16 + l15;
                bfr[n] = __builtin_bit_cast(bf16x8,
                    *(const uint4*)(BsB + col * 128 + ((kk * 64 + q * 16) ^ ((col & 7) << 4))));
            }
#pragma unroll
            for (int m = 0; m < 2; ++m)
#pragma unroll
                for (int n = 0; n < 4; ++n)
                    acc[m][n] = __builtin_amdgcn_mfma_f32_16x16x32_bf16(af[m], bfr[n], acc[m][n], 0, 0, 0);
        }
    }
#pragma unroll
    for (int m = 0; m < 2; ++m) {
        int rb = row0 + wr * 32 + m * 16 + q * 4;
#pragma unroll
        for (int n = 0; n < 4; ++n) {
            int c = wc * 64 + n * 16 + l15;
#pragma unroll
            for (int e = 0; e < 4; ++e)
                Apart[((int64_t)t * 1024 + rb + e) * 128 + c] = acc[m][n][e];
        }
    }
}

// ---------------- fused GCN layer: hw = Hin@W; h = relu((sl*hw + Apart + b)*scale + bnb) + Hin
// Output staged via LDS (BsB reused) -> coalesced uint4 stores.
__global__ __launch_bounds__(256) void gcn_fused(const ushort_t* __restrict__ Hin,
                                                 const ushort_t* __restrict__ Wt,
                                                 const float* __restrict__ Apart,
                                                 const float* __restrict__ dis,
                                                 const float* __restrict__ gcnb,
                                                 const float* __restrict__ bng,
                                                 const float* __restrict__ bnb,
                                                 ushort_t* __restrict__ Hout) {
    __shared__ __align__(16) char AsB[32768];
    __shared__ __align__(16) char BsB[32768];
    const int tid = threadIdx.x, lane = tid & 63, wid = tid >> 6;
    const int wr = wid >> 1, wc = wid & 1, q = lane >> 4, l15 = lane & 15;
    const int64_t row0 = (int64_t)blockIdx.x * 128;
    const ushort_t* Ap = Hin + row0 * 128;
    f32x4 acc[4][4];
#pragma unroll
    for (int m = 0; m < 4; ++m)
#pragma unroll
        for (int n = 0; n < 4; ++n) acc[m][n] = f32x4{0.f, 0.f, 0.f, 0.f};
#pragma unroll
    for (int i = 0; i < 8; ++i) {
        int id = i * 256 + tid; int r = id >> 4, sg = id & 15;
        uint4 va = *(const uint4*)(Ap + r * 128 + sg * 8);
        *(uint4*)(AsB + r * 256 + ((sg * 16) ^ ((r & 7) << 4))) = va;
        uint4 vb = *(const uint4*)(Wt + r * 128 + sg * 8);
        *(uint4*)(BsB + r * 256 + ((sg * 16) ^ ((r & 7) << 4))) = vb;
    }
    __syncthreads();
#pragma unroll
    for (int kk = 0; kk < 4; ++kk) {
        bf16x8 af[4], bfr[4];
#pragma unroll
        for (int m = 0; m < 4; ++m) {
            int row = wr * 64 + m * 16 + l15;
            af[m] = __builtin_bit_cast(bf16x8,
                *(const uint4*)(AsB + row * 256 + ((kk * 64 + q * 16) ^ ((row & 7) << 4))));
        }
#pragma unroll
        for (int n = 0; n < 4; ++n) {
            int col = wc * 64 + n * 16 + l15;
            bfr[n] = __builtin_bit_cast(bf16x8,
                *(const uint4*)(BsB + col * 256 + ((kk * 64 + q * 16) ^ ((col & 7) << 4))));
        }
#pragma unroll
        for (int m = 0; m < 4; ++m)
#pragma unroll
            for (int n = 0; n < 4; ++n)
                acc[m][n] = __builtin_amdgcn_mfma_f32_16x16x32_bf16(af[m], bfr[n], acc[m][n], 0, 0, 0);
    }
    __syncthreads();   // all BsB (weight) frag reads done; BsB becomes out-tile
    const int bn0 = (int)(row0 & 8191);
    const int t = (int)(row0 >> 13);
    const bool hasA = bn0 < 1024;
    const float rs = rsqrtf(1.f + EPS);
#pragma unroll
    for (int n = 0; n < 4; ++n) {
        int col = wc * 64 + n * 16 + l15;
        float gb = gcnb[col], sc = bng[col] * rs, bb = bnb[col];
        int seg16 = (col >> 3) * 16, wb = (col & 7) * 2;
#pragma unroll
        for (int m = 0; m < 4; ++m) {
            int rl0 = wr * 64 + m * 16 + q * 4;
#pragma unroll
            for (int e = 0; e < 4; ++e) {
                int rl = rl0 + e;
                int bn = bn0 + rl;
                float sl = dis[bn]; sl *= sl;
                float mv = sl * acc[m][n][e] + gb;
                if (hasA) mv += Apart[((int64_t)t * 1024 + bn) * 128 + col];
                ushort_t rbv = *(const ushort_t*)(AsB + rl * 256 + (seg16 ^ ((rl & 7) << 4)) + wb);
                float v = fmaxf(mv * sc + bb, 0.f) + bf2f(rbv);
                *(ushort_t*)(BsB + rl * 256 + (seg16 ^ ((rl & 7) << 4)) + wb) = f2bf(v);
            }
        }
    }
    __syncthreads();
#pragma unroll
    for (int i = 0; i < 8; ++i) {
        int id = i * 256 + tid; int r = id >> 4, sg = id & 15;
        uint4 v = *(const uint4*)(BsB + r * 256 + ((sg * 16) ^ ((r & 7) << 4)));
        *(uint4*)(Hout + (row0 + r) * 128 + sg * 8) = v;
    }
}

// ---------------- one LSTM layer, weights held in VGPRs.
// 256 blocks x 512 threads (8 waves, 2 blocks/CU). Block owns 32 rows for all 16
// steps. Wave w owns gate-cols' [w*64,(w+1)*64) = hidden [w*16,w*16+16); its
// Wi/Wh slices (16KB each) are preloaded into 128 VGPRs. h in LDS, c in VGPRs.
// Per step the only global traffic: 8KB coalesced X read (+8KB y write).
__global__ __launch_bounds__(512, 2) void lstm_layer(
    const ushort_t* __restrict__ X,        // [16][8192][128]
    const ushort_t* __restrict__ Wi, const ushort_t* __restrict__ Wh,
    const float* __restrict__ bs,          // [512] gate-interleaved
    ushort_t* __restrict__ Y,              // [16][8192][128] per-step out (or null)
    ushort_t* __restrict__ Hfinal) {       // [8192][128] final h (or null)
    __shared__ __align__(16) char Xs[8192];   // 32 rows x 256B (swizzled)
    __shared__ __align__(16) char Hs[8192];
    const int tid = threadIdx.x, lane = tid & 63, w = tid >> 6;
    const int q = lane >> 4, l15 = lane & 15;
    const int row0 = blockIdx.x * 32;

    *(uint4*)(Xs + tid * 16) = uint4{0, 0, 0, 0};     // (touch; not required)
    *(uint4*)(Hs + tid * 16) = uint4{0, 0, 0, 0};     // zero h0

    // preload this wave's weight slices into registers
    bf16x8 wi[4][4], wh[4][4];
#pragma unroll
    for (int n = 0; n < 4; ++n)
#pragma unroll
        for (int kk = 0; kk < 4; ++kk) {
            int col = w * 64 + n * 16 + l15;
            wi[n][kk] = __builtin_bit_cast(bf16x8, *(const uint4*)(Wi + col * 128 + kk * 32 + q * 8));
            wh[n][kk] = __builtin_bit_cast(bf16x8, *(const uint4*)(Wh + col * 128 + kk * 32 + q * 8));
        }
    const int cb = w * 64 + l15;
    const float bi = bs[cb], bf = bs[cb + 16], bg = bs[cb + 32], bo = bs[cb + 48];
    const int k = w * 16 + l15;                       // this lane's hidden unit
    float c[2][4] = {};
    __syncthreads();

    for (int t = 0; t < 16; ++t) {
        // stage X[t] rows (coalesced, swizzled): 512 threads x 16B = 8KB
        {
            int r = tid >> 4, sg = tid & 15;
            uint4 v = *(const uint4*)(X + ((int64_t)t * 8192 + row0 + r) * 128 + sg * 8);
            *(uint4*)(Xs + r * 256 + ((sg * 16) ^ ((r & 7) << 4))) = v;
        }
        __syncthreads();

        f32x4 acc[2][4];
#pragma unroll
        for (int m = 0; m < 2; ++m)
#pragma unroll
            for (int n = 0; n < 4; ++n) acc[m][n] = f32x4{0.f, 0.f, 0.f, 0.f};
#pragma unroll
        for (int kk = 0; kk < 4; ++kk) {
            bf16x8 ax[2], ah[2];
#pragma unroll
            for (int m = 0; m < 2; ++m) {
                int row = m * 16 + l15;
                int off = row * 256 + ((kk * 64 + q * 16) ^ ((row & 7) << 4));
                ax[m] = __builtin_bit_cast(bf16x8, *(const uint4*)(Xs + off));
                ah[m] = __builtin_bit_cast(bf16x8, *(const uint4*)(Hs + off));
            }
#pragma unroll
            for (int n = 0; n < 4; ++n)
#pragma unroll
                for (int m = 0; m < 2; ++m) {
                    acc[m][n] = __builtin_amdgcn_mfma_f32_16x16x32_bf16(ax[m], wi[n][kk], acc[m][n], 0, 0, 0);
                    acc[m][n] = __builtin_amdgcn_mfma_f32_16x16x32_bf16(ah[m], wh[n][kk], acc[m][n], 0, 0, 0);
                }
        }
        __syncthreads();   // all Hs reads done before overwrite

        // fused cell: n = gate (i,f,g,o) of hidden k; rows m*16+q*4+e
#pragma unroll
        for (int m = 0; m < 2; ++m)
#pragma unroll
            for (int e = 0; e < 4; ++e) {
                float ig = sigm_fast(acc[m][0][e] + bi);
                float fg = sigm_fast(acc[m][1][e] + bf);
                float gg = tanh_fast(acc[m][2][e] + bg);
                float og = sigm_fast(acc[m][3][e] + bo);
                float cn = fg * c[m][e] + ig * gg;
                c[m][e] = cn;
                float hn = og * tanh_fast(cn);
                int row = m * 16 + q * 4 + e;
                int byte = row * 256 + ((((k >> 3) * 16) ^ ((row & 7) << 4)) | ((k & 7) * 2));
                *(ushort_t*)(Hs + byte) = f2bf(hn);
            }
        __syncthreads();   // new h complete

        if (Y) {           // coalesced y[t] write from LDS
            int r = tid >> 4, sg = tid & 15;
            uint4 v = *(const uint4*)(Hs + r * 256 + ((sg * 16) ^ ((r & 7) << 4)));
            *(uint4*)(Y + ((int64_t)t * 8192 + row0 + r) * 128 + sg * 8) = v;
        }
    }
    if (Hfinal) {
        int r = tid >> 4, sg = tid & 15;
        uint4 v = *(const uint4*)(Hs + r * 256 + ((sg * 16) ^ ((r & 7) << 4)));
        *(uint4*)(Hfinal + (int64_t)(row0 + r) * 128 + sg * 8) = v;
    }
}

// ---------------- output head
__global__ __launch_bounds__(64) void out_head(const ushort_t* __restrict__ y,
                                               const float* __restrict__ w1,
                                               const float* __restrict__ b1,
                                               const float* __restrict__ g,
                                               const float* __restrict__ be,
                                               const float* __restrict__ w2,
                                               const float* __restrict__ b2,
                                               float* __restrict__ out) {
    int r = blockIdx.x;  // 0..8191
    int j = threadIdx.x; // 0..63
    const ushort_t* yr = y + (int64_t)r * 128;
    float acc = b1[j];
    for (int k = 0; k < 128; ++k) acc += bf2f(yr[k]) * w1[k * 64 + j];
    float s = acc;
    for (int off = 32; off; off >>= 1) s += __shfl_xor(s, off, 64);
    float mu = s * (1.f / 64.f);
    float d = acc - mu;
    float vs = d * d;
    for (int off = 32; off; off >>= 1) vs += __shfl_xor(vs, off, 64);
    float var = vs * (1.f / 64.f);
    float z = fmaxf(d * rsqrtf(var + EPS) * g[j] + be[j], 0.f);
    float p = z * w2[j];
    for (int off = 32; off; off >>= 1) p += __shfl_xor(p, off, 64);
    if (j == 0) out[r] = p + b2[0];
}

extern "C" void kernel_launch(void* const* d_in, const int* in_sizes, int n_in,
                              void* d_out, int out_size, void* d_ws, size_t ws_size,
                              hipStream_t stream) {
    const float* x    = (const float*)d_in[0];
    const int*   eidx = (const int*)d_in[1];
    const float* ewt  = (const float*)d_in[2];
    const float* efeat= (const float*)d_in[3];
    const float* w_in = (const float*)d_in[4];
    const float* b_in = (const float*)d_in[5];
    const float* lng  = (const float*)d_in[6];
    const float* lnb  = (const float*)d_in[7];
    const float* we1  = (const float*)d_in[8];
    const float* be1  = (const float*)d_in[9];
    const float* we2  = (const float*)d_in[10];
    const float* be2  = (const float*)d_in[11];
    const float* gcnw = (const float*)d_in[12];
    const float* gcnb = (const float*)d_in[13];
    const float* bng  = (const float*)d_in[14];
    const float* bnb  = (const float*)d_in[15];
    const float* wih  = (const float*)d_in[16];
    const float* whh  = (const float*)d_in[17];
    const float* bih  = (const float*)d_in[18];
    const float* bhh  = (const float*)d_in[19];
    const float* wo1  = (const float*)d_in[20];
    const float* bo1  = (const float*)d_in[21];
    const float* lnog = (const float*)d_in[22];
    const float* lnob = (const float*)d_in[23];
    const float* wo2  = (const float*)d_in[24];
    const float* bo2  = (const float*)d_in[25];
    float* out = (float*)d_out;

    // ---- workspace layout (~85MB)
    char* W = (char*)d_ws;
    ushort_t* hcur_bf   = (ushort_t*)(W);                        // 32MB [16][8192][128]
    ushort_t* y1        = (ushort_t*)(W + (32ll << 20));         // 32MB layer-1 outputs
    ushort_t* hwT       = (ushort_t*)(W + (64ll << 20));         // 4MB  [16][128][1024]
    float*    Apart     = (float*)(W + (68ll << 20));            // 8MB  [16][1024][128]
    float*    Adense    = (float*)(W + (76ll << 20));            // 4MB
    ushort_t* Adense_bf = (ushort_t*)(W + (80ll << 20));         // 2MB
    ushort_t* h2out     = (ushort_t*)(W + (82ll << 20));         // 2MB [8192][128]
    float*    ew        = (float*)(W + (84ll << 20));            // 128KB
    float*    dis       = (float*)(W + (84ll << 20) + 0x20000);  // 32KB
    float*    bsg       = (float*)(W + (84ll << 20) + 0x28000);  // 4KB [2][512]
    ushort_t* gcnwT     = (ushort_t*)(W + (84ll << 20) + 0x30000); // 128KB
    ushort_t* wgi       = (ushort_t*)(W + (84ll << 20) + 0x50000); // 256KB [2][512][128]
    ushort_t* wgh       = (ushort_t*)(W + (84ll << 20) + 0x90000); // 256KB

    const int* srcI = eidx;
    const int* dstI = eidx + 32768;

    // graph preprocessing
    edge_att<<<128, 256, 0, stream>>>(efeat, we1, be1, we2, be2, ewt, ew);
    deg_init<<<32, 256, 0, stream>>>(dis);
    deg_acc<<<128, 256, 0, stream>>>(dstI, ew, dis);
    make_dis<<<32, 256, 0, stream>>>(dis);
    hipMemsetAsync(Adense, 0, 1048576 * sizeof(float), stream);
    scatterA<<<128, 256, 0, stream>>>(srcI, dstI, ew, dis, Adense);
    convF2B<<<4096, 256, 0, stream>>>(Adense, Adense_bf, 1048576);

    // weight conversions
    convW<<<256, 256, 0, stream>>>(gcnw, gcnwT);
    conv_lstm_w<<<512, 256, 0, stream>>>(wih, whh, wgi, wgh);
    conv_lstm_b<<<4, 256, 0, stream>>>(bih, bhh, bsg);

    // input projection (bf16 only)
    in_proj_ln<<<23552, 128, 0, stream>>>(x, w_in, b_in, lng, lnb, hcur_bf);

    // GCN layers
    for (int l = 0; l < 4; ++l) {
        gemm_feat_t<<<dim3(8, 16, 1), 256, 0, stream>>>(hcur_bf, gcnwT + l * 16384, hwT);
        gemm_adj<<<dim3(16, 1, 16), 256, 0, stream>>>(Adense_bf, hwT, Apart);
        gcn_fused<<<1024, 256, 0, stream>>>(hcur_bf, gcnwT + l * 16384, Apart, dis,
                                            gcnb + l * 128, bng + l * 128, bnb + l * 128,
                                            hcur_bf);
    }

    // LSTM: two dispatches, weights in VGPRs, c in VGPRs, h in LDS
    lstm_layer<<<256, 512, 0, stream>>>(hcur_bf, wgi, wgh, bsg, y1, nullptr);
    lstm_layer<<<256, 512, 0, stream>>>(y1, wgi + 65536, wgh + 65536, bsg + 512,
                                        nullptr, h2out);

    // output head
    out_head<<<8192, 64, 0, stream>>>(h2out, wo1, bo1, lnog, lnob, wo2, bo2, out);
}

// Round 7
// 349.760 us; speedup vs baseline: 2.4985x; 1.2116x over previous
//
#include <hip/hip_runtime.h>
#include <cstdint>

// B=8, S=16, N=1024, F=16, H=128, E=32768, L=4, BN=8192
#define EPS 1e-5f

typedef unsigned short ushort_t;
typedef __bf16 bf16x8 __attribute__((ext_vector_type(8)));
typedef float f32x4 __attribute__((ext_vector_type(4)));

__device__ __forceinline__ float sigm(float x) { return 1.f / (1.f + expf(-x)); }
__device__ __forceinline__ unsigned short f2bf(float f) {
    unsigned int u = __builtin_bit_cast(unsigned int, f);
    return (unsigned short)((u + 0x7fffu + ((u >> 16) & 1u)) >> 16);
}
__device__ __forceinline__ float bf2f(unsigned short s) {
    unsigned int u = ((unsigned int)s) << 16;
    return __builtin_bit_cast(float, u);
}
__device__ __forceinline__ float sigm_fast(float x) {
    float t = __builtin_amdgcn_exp2f(-1.44269504f * x);
    return __builtin_amdgcn_rcpf(1.f + t);
}
__device__ __forceinline__ float tanh_fast(float x) {
    float xc = fminf(fmaxf(x, -15.f), 15.f);
    float t = __builtin_amdgcn_exp2f(-2.88539008f * xc);
    return (1.f - t) * __builtin_amdgcn_rcpf(1.f + t);
}

// ---------------- edge attention + degree accumulate (deg pre-zeroed; self-loop added later)
__global__ __launch_bounds__(256) void edge_att_deg(const float* __restrict__ ef,
                                                    const float* __restrict__ we1,
                                                    const float* __restrict__ be1,
                                                    const float* __restrict__ we2,
                                                    const float* __restrict__ be2,
                                                    const float* __restrict__ ewin,
                                                    const int* __restrict__ dst,
                                                    float* __restrict__ ew,
                                                    float* __restrict__ deg) {
    int e = blockIdx.x * blockDim.x + threadIdx.x;
    if (e >= 32768) return;
    float x = ef[e];
    float acc = 0.f;
    for (int h = 0; h < 128; ++h) {
        float v = fmaxf(x * we1[h] + be1[h], 0.f);
        acc += v * we2[h];
    }
    float wv = ewin[e] * sigm(acc + be2[0]);
    ew[e] = wv;
    atomicAdd(&deg[dst[e]], wv);
}
__global__ __launch_bounds__(256) void make_dis(float* __restrict__ deg) {
    int i = blockIdx.x * blockDim.x + threadIdx.x;
    if (i < 1024) { float d = deg[i] + 1.0f; deg[i] = (d > 0.f) ? rsqrtf(d) : 0.f; }
}
__global__ __launch_bounds__(256) void scatterA(const int* __restrict__ src,
                                                const int* __restrict__ dst,
                                                const float* __restrict__ ew,
                                                const float* __restrict__ dis,
                                                float* __restrict__ A) {
    int e = blockIdx.x * blockDim.x + threadIdx.x;
    if (e >= 32768) return;
    int s = src[e], d = dst[e];
    atomicAdd(&A[d * 1024 + s], dis[s] * ew[e] * dis[d]);
}

// ---------------- converters
__global__ __launch_bounds__(256) void convF2B(const float* __restrict__ s,
                                               ushort_t* __restrict__ d, int n) {
    int i = blockIdx.x * blockDim.x + threadIdx.x;
    if (i < n) d[i] = f2bf(s[i]);
}
// merged weight conversions: gcnwT | lstm gate-interleaved weights | gate-interleaved bias
__global__ __launch_bounds__(256) void conv_all(const float* __restrict__ gcnw,
                                                const float* __restrict__ wih,
                                                const float* __restrict__ whh,
                                                const float* __restrict__ bih,
                                                const float* __restrict__ bhh,
                                                ushort_t* __restrict__ gcnwT,
                                                ushort_t* __restrict__ wgi,
                                                ushort_t* __restrict__ wgh,
                                                float* __restrict__ bsg) {
    int i = blockIdx.x * 256 + threadIdx.x;
    if (i < 65536) {                       // gcnw [l][in][out] -> [l][out][in] bf16
        int l = i >> 14, rem = i & 16383, in = rem >> 7, outc = rem & 127;
        gcnwT[l * 16384 + outc * 128 + in] = f2bf(gcnw[i]);
        return;
    }
    int j = i - 65536;
    if (j < 131072) {                      // col' = (h>>4)*64 + gate*16 + (h&15)
        int l = j >> 16, rem = j & 65535, c = rem >> 7, kx = rem & 127;
        int g = (c >> 4) & 3, h = (c >> 6) * 16 + (c & 15);
        int src = (l * 512 + g * 128 + h) * 128 + kx;
        wgi[j] = f2bf(wih[src]);
        wgh[j] = f2bf(whh[src]);
        return;
    }
    int b = j - 131072;
    if (b < 1024) {
        int l = b >> 9, c = b & 511;
        int g = (c >> 4) & 3, h = (c >> 6) * 16 + (c & 15);
        int src = l * 512 + g * 128 + h;
        bsg[b] = bih[src] + bhh[src];
    }
}

// ---------------- input projection + LN + ReLU -> compact hA[t=k][n] (k<16) and hB[k][n]
__global__ __launch_bounds__(128) void in_proj_ln(const float* __restrict__ x,
                                                  const float* __restrict__ w,
                                                  const float* __restrict__ bias,
                                                  const float* __restrict__ g,
                                                  const float* __restrict__ be,
                                                  ushort_t* __restrict__ hA,
                                                  ushort_t* __restrict__ hB) {
    int r = blockIdx.x;            // k*1024 + n, k in [0,23)
    int h = threadIdx.x;
    int k = r >> 10, n = r & 1023;
    __shared__ float xs[16];
    __shared__ float red[128];
    if (h < 16) xs[h] = x[(int64_t)r * 16 + h];
    __syncthreads();
    float acc = bias[h];
#pragma unroll
    for (int f = 0; f < 16; ++f) acc += xs[f] * w[f * 128 + h];
    red[h] = acc; __syncthreads();
    for (int off = 64; off; off >>= 1) { if (h < off) red[h] += red[h + off]; __syncthreads(); }
    float mu = red[0] * (1.f / 128.f); __syncthreads();
    float d = acc - mu; red[h] = d * d; __syncthreads();
    for (int off = 64; off; off >>= 1) { if (h < off) red[h] += red[h + off]; __syncthreads(); }
    float var = red[0] * (1.f / 128.f);
    float v = fmaxf(d * rsqrtf(var + EPS) * g[h] + be[h], 0.f);
    ushort_t vb = f2bf(v);
    int64_t idx = ((int64_t)k * 1024 + n) * 128 + h;
    if (k < 16) hA[idx] = vb;
    hB[idx] = vb;
}

// ---------------- feature GEMM from hA (16x1024 rows), transposed output hwT[t][col][bn]
__global__ __launch_bounds__(256) void gemm_feat_t(const ushort_t* __restrict__ hA,
                                                   const ushort_t* __restrict__ Wt,
                                                   ushort_t* __restrict__ hwT) {
    __shared__ __align__(16) char AsB[32768];
    __shared__ __align__(16) char BsB[32768];
    const int tid = threadIdx.x, lane = tid & 63, wid = tid >> 6;
    const int wr = wid >> 1, wc = wid & 1, q = lane >> 4, l15 = lane & 15;
    const int t = blockIdx.y;
    const int row0 = blockIdx.x * 128;
    const ushort_t* Ap = hA + ((int64_t)t * 1024 + row0) * 128;
    f32x4 acc[4][4];
#pragma unroll
    for (int m = 0; m < 4; ++m)
#pragma unroll
        for (int n = 0; n < 4; ++n) acc[m][n] = f32x4{0.f, 0.f, 0.f, 0.f};
#pragma unroll
    for (int i = 0; i < 8; ++i) {
        int id = i * 256 + tid; int r = id >> 4, sg = id & 15;
        uint4 va = *(const uint4*)(Ap + r * 128 + sg * 8);
        *(uint4*)(AsB + r * 256 + ((sg * 16) ^ ((r & 7) << 4))) = va;
        uint4 vb = *(const uint4*)(Wt + r * 128 + sg * 8);
        *(uint4*)(BsB + r * 256 + ((sg * 16) ^ ((r & 7) << 4))) = vb;
    }
    __syncthreads();
#pragma unroll
    for (int kk = 0; kk < 4; ++kk) {
        bf16x8 af[4], bfr[4];
#pragma unroll
        for (int m = 0; m < 4; ++m) {
            int row = wr * 64 + m * 16 + l15;
            af[m] = __builtin_bit_cast(bf16x8,
                *(const uint4*)(AsB + row * 256 + ((kk * 64 + q * 16) ^ ((row & 7) << 4))));
        }
#pragma unroll
        for (int n = 0; n < 4; ++n) {
            int col = wc * 64 + n * 16 + l15;
            bfr[n] = __builtin_bit_cast(bf16x8,
                *(const uint4*)(BsB + col * 256 + ((kk * 64 + q * 16) ^ ((col & 7) << 4))));
        }
#pragma unroll
        for (int m = 0; m < 4; ++m)
#pragma unroll
            for (int n = 0; n < 4; ++n)
                acc[m][n] = __builtin_amdgcn_mfma_f32_16x16x32_bf16(af[m], bfr[n], acc[m][n], 0, 0, 0);
    }
#pragma unroll
    for (int m = 0; m < 4; ++m) {
        int bn = row0 + wr * 64 + m * 16 + q * 4;
#pragma unroll
        for (int n = 0; n < 4; ++n) {
            int col = wc * 64 + n * 16 + l15;
            ushort4 u;
            u.x = f2bf(acc[m][n][0]); u.y = f2bf(acc[m][n][1]);
            u.z = f2bf(acc[m][n][2]); u.w = f2bf(acc[m][n][3]);
            *(ushort4*)(hwT + ((int64_t)t * 128 + col) * 1024 + bn) = u;
        }
    }
}

// ---------------- adjacency GEMM: Apart[t] = Adense_bf @ hw[t]  (B as hwT [col][bn])
__global__ __launch_bounds__(256) void gemm_adj(const ushort_t* __restrict__ Abf,
                                                const ushort_t* __restrict__ hwT,
                                                float* __restrict__ Apart) {
    __shared__ __align__(16) char AsB[8192];
    __shared__ __align__(16) char BsB[16384];
    const int tid = threadIdx.x, lane = tid & 63, wid = tid >> 6;
    const int wr = wid >> 1, wc = wid & 1, q = lane >> 4, l15 = lane & 15;
    const int row0 = blockIdx.x * 64;
    const int t = blockIdx.z;
    const ushort_t* Bp = hwT + (int64_t)t * 131072;
    f32x4 acc[2][4];
#pragma unroll
    for (int m = 0; m < 2; ++m)
#pragma unroll
        for (int n = 0; n < 4; ++n) acc[m][n] = f32x4{0.f, 0.f, 0.f, 0.f};
    for (int k0 = 0; k0 < 1024; k0 += 64) {
        __syncthreads();
#pragma unroll
        for (int i = 0; i < 2; ++i) {
            int id = i * 256 + tid; int r = id >> 3, sg = id & 7;
            uint4 v = *(const uint4*)(Abf + (int64_t)(row0 + r) * 1024 + k0 + sg * 8);
            *(uint4*)(AsB + r * 128 + ((sg * 16) ^ ((r & 7) << 4))) = v;
        }
#pragma unroll
        for (int i = 0; i < 4; ++i) {
            int id = i * 256 + tid; int r = id >> 3, sg = id & 7;
            uint4 v = *(const uint4*)(Bp + (int64_t)r * 1024 + k0 + sg * 8);
            *(uint4*)(BsB + r * 128 + ((sg * 16) ^ ((r & 7) << 4))) = v;
        }
        __syncthreads();
#pragma unroll
        for (int kk = 0; kk < 2; ++kk) {
            bf16x8 af[2], bfr[4];
#pragma unroll
            for (int m = 0; m < 2; ++m) {
                int row = wr * 32 + m * 16 + l15;
                af[m] = __builtin_bit_cast(bf16x8,
                    *(const uint4*)(AsB + row * 128 + ((kk * 64 + q * 16) ^ ((row & 7) << 4))));
            }
#pragma unroll
            for (int n = 0; n < 4; ++n) {
                int col = wc * 64 + n * 16 + l15;
                bfr[n] = __builtin_bit_cast(bf16x8,
                    *(const uint4*)(BsB + col * 128 + ((kk * 64 + q * 16) ^ ((col & 7) << 4))));
            }
#pragma unroll
            for (int m = 0; m < 2; ++m)
#pragma unroll
                for (int n = 0; n < 4; ++n)
                    acc[m][n] = __builtin_amdgcn_mfma_f32_16x16x32_bf16(af[m], bfr[n], acc[m][n], 0, 0, 0);
        }
    }
#pragma unroll
    for (int m = 0; m < 2; ++m) {
        int rb = row0 + wr * 32 + m * 16 + q * 4;
#pragma unroll
        for (int n = 0; n < 4; ++n) {
            int c = wc * 64 + n * 16 + l15;
#pragma unroll
            for (int e = 0; e < 4; ++e)
                Apart[((int64_t)t * 1024 + rb + e) * 128 + c] = acc[m][n][e];
        }
    }
}

// ---------------- fused GCN layer over compact state.
// blocks [0,128): hA (adjacency+dis); blocks [128,312): hB (sl=1, no Apart).
__global__ __launch_bounds__(256) void gcn_fused(ushort_t* __restrict__ hA,
                                                 ushort_t* __restrict__ hB,
                                                 const ushort_t* __restrict__ Wt,
                                                 const float* __restrict__ Apart,
                                                 const float* __restrict__ dis,
                                                 const float* __restrict__ gcnb,
                                                 const float* __restrict__ bng,
                                                 const float* __restrict__ bnb) {
    __shared__ __align__(16) char AsB[32768];
    __shared__ __align__(16) char BsB[32768];
    const int tid = threadIdx.x, lane = tid & 63, wid = tid >> 6;
    const int wr = wid >> 1, wc = wid & 1, q = lane >> 4, l15 = lane & 15;
    const int bx = blockIdx.x;
    const bool adj = bx < 128;
    const int lb2 = adj ? bx : bx - 128;
    const int tt = lb2 >> 3;
    const int n0 = (lb2 & 7) * 128;
    ushort_t* Ap = (adj ? hA : hB) + ((int64_t)tt * 1024 + n0) * 128;
    f32x4 acc[4][4];
#pragma unroll
    for (int m = 0; m < 4; ++m)
#pragma unroll
        for (int n = 0; n < 4; ++n) acc[m][n] = f32x4{0.f, 0.f, 0.f, 0.f};
#pragma unroll
    for (int i = 0; i < 8; ++i) {
        int id = i * 256 + tid; int r = id >> 4, sg = id & 15;
        uint4 va = *(const uint4*)(Ap + r * 128 + sg * 8);
        *(uint4*)(AsB + r * 256 + ((sg * 16) ^ ((r & 7) << 4))) = va;
        uint4 vb = *(const uint4*)(Wt + r * 128 + sg * 8);
        *(uint4*)(BsB + r * 256 + ((sg * 16) ^ ((r & 7) << 4))) = vb;
    }
    __syncthreads();
#pragma unroll
    for (int kk = 0; kk < 4; ++kk) {
        bf16x8 af[4], bfr[4];
#pragma unroll
        for (int m = 0; m < 4; ++m) {
            int row = wr * 64 + m * 16 + l15;
            af[m] = __builtin_bit_cast(bf16x8,
                *(const uint4*)(AsB + row * 256 + ((kk * 64 + q * 16) ^ ((row & 7) << 4))));
        }
#pragma unroll
        for (int n = 0; n < 4; ++n) {
            int col = wc * 64 + n * 16 + l15;
            bfr[n] = __builtin_bit_cast(bf16x8,
                *(const uint4*)(BsB + col * 256 + ((kk * 64 + q * 16) ^ ((col & 7) << 4))));
        }
#pragma unroll
        for (int m = 0; m < 4; ++m)
#pragma unroll
            for (int n = 0; n < 4; ++n)
                acc[m][n] = __builtin_amdgcn_mfma_f32_16x16x32_bf16(af[m], bfr[n], acc[m][n], 0, 0, 0);
    }
    __syncthreads();   // weight frag reads done; BsB becomes out-tile
    const float rs = rsqrtf(1.f + EPS);
#pragma unroll
    for (int n = 0; n < 4; ++n) {
        int col = wc * 64 + n * 16 + l15;
        float gb = gcnb[col], sc = bng[col] * rs, bb = bnb[col];
        int seg16 = (col >> 3) * 16, wb = (col & 7) * 2;
#pragma unroll
        for (int m = 0; m < 4; ++m) {
            int rl0 = wr * 64 + m * 16 + q * 4;
#pragma unroll
            for (int e = 0; e < 4; ++e) {
                int rl = rl0 + e;
                float sl = 1.f;
                if (adj) { float dv = dis[n0 + rl]; sl = dv * dv; }
                float mv = sl * acc[m][n][e] + gb;
                if (adj) mv += Apart[((int64_t)tt * 1024 + n0 + rl) * 128 + col];
                ushort_t rbv = *(const ushort_t*)(AsB + rl * 256 + (seg16 ^ ((rl & 7) << 4)) + wb);
                float v = fmaxf(mv * sc + bb, 0.f) + bf2f(rbv);
                *(ushort_t*)(BsB + rl * 256 + (seg16 ^ ((rl & 7) << 4)) + wb) = f2bf(v);
            }
        }
    }
    __syncthreads();
#pragma unroll
    for (int i = 0; i < 8; ++i) {
        int id = i * 256 + tid; int r = id >> 4, sg = id & 15;
        uint4 v = *(const uint4*)(BsB + r * 256 + ((sg * 16) ^ ((r & 7) << 4)));
        *(uint4*)(Ap + r * 128 + sg * 8) = v;
    }
}

// ---------------- LSTM layer, weights in VGPRs, X register-prefetch, 2 barriers/step.
// MODE 0: gather X from compact hA/hB, write Y per step.
// MODE 1: read X flat; fused output head (Linear+LN+ReLU+Linear) at the end.
template <int MODE>
__global__ __launch_bounds__(512, 2) void lstm_layer(
    const ushort_t* __restrict__ hA, const ushort_t* __restrict__ hB,
    const ushort_t* __restrict__ X,
    const ushort_t* __restrict__ Wi, const ushort_t* __restrict__ Wh,
    const float* __restrict__ bs,
    ushort_t* __restrict__ Y,
    const float* __restrict__ w1, const float* __restrict__ b1,
    const float* __restrict__ lg, const float* __restrict__ lb,
    const float* __restrict__ w2, const float* __restrict__ b2,
    float* __restrict__ out) {
    __shared__ __align__(16) char Xs[8192];
    __shared__ __align__(16) char Hs[8192];
    __shared__ __align__(16) char W1s[32768];
    const int tid = threadIdx.x, lane = tid & 63, w = tid >> 6;
    const int q = lane >> 4, l15 = lane & 15;
    const int row0 = blockIdx.x * 32;
    const int r = tid >> 4, sg = tid & 15;
    const int bb = row0 >> 10, n0 = row0 & 1023;

    *(uint4*)(Hs + tid * 16) = uint4{0, 0, 0, 0};
    if constexpr (MODE == 1) {
#pragma unroll
        for (int i = 0; i < 4; ++i)
            *(uint4*)(W1s + (i * 512 + tid) * 16) =
                *(const uint4*)((const char*)w1 + (i * 512 + tid) * 16);
    }
    // preload this wave's weight slices into registers
    bf16x8 wi[4][4], wh[4][4];
#pragma unroll
    for (int n = 0; n < 4; ++n)
#pragma unroll
        for (int kk = 0; kk < 4; ++kk) {
            int col = w * 64 + n * 16 + l15;
            wi[n][kk] = __builtin_bit_cast(bf16x8, *(const uint4*)(Wi + col * 128 + kk * 32 + q * 8));
            wh[n][kk] = __builtin_bit_cast(bf16x8, *(const uint4*)(Wh + col * 128 + kk * 32 + q * 8));
        }
    const int cb = w * 64 + l15;
    const float bi = bs[cb], bf = bs[cb + 16], bg = bs[cb + 32], bo = bs[cb + 48];
    const int k = w * 16 + l15;
    float c[2][4] = {};

    auto xsrc = [&](int t) -> const ushort_t* {
        if constexpr (MODE == 0)
            return (bb == 0) ? hA + ((int64_t)t * 1024 + n0) * 128
                             : hB + ((int64_t)(t + bb) * 1024 + n0) * 128;
        else
            return X + ((int64_t)t * 8192 + row0) * 128;
    };

    uint4 xn = *(const uint4*)(xsrc(0) + r * 128 + sg * 8);
    *(uint4*)(Xs + r * 256 + ((sg * 16) ^ ((r & 7) << 4))) = xn;
    __syncthreads();

    for (int t = 0; t < 16; ++t) {
        // prefetch next X into registers; latency hides under MFMA phase
        xn = *(const uint4*)(xsrc(t < 15 ? t + 1 : 15) + r * 128 + sg * 8);

        f32x4 acc[2][4];
#pragma unroll
        for (int m = 0; m < 2; ++m)
#pragma unroll
            for (int n = 0; n < 4; ++n) acc[m][n] = f32x4{0.f, 0.f, 0.f, 0.f};
#pragma unroll
        for (int kk = 0; kk < 4; ++kk) {
            bf16x8 ax[2], ah[2];
#pragma unroll
            for (int m = 0; m < 2; ++m) {
                int rw = m * 16 + l15;
                int off = rw * 256 + ((kk * 64 + q * 16) ^ ((rw & 7) << 4));
                ax[m] = __builtin_bit_cast(bf16x8, *(const uint4*)(Xs + off));
                ah[m] = __builtin_bit_cast(bf16x8, *(const uint4*)(Hs + off));
            }
#pragma unroll
            for (int n = 0; n < 4; ++n)
#pragma unroll
                for (int m = 0; m < 2; ++m) {
                    acc[m][n] = __builtin_amdgcn_mfma_f32_16x16x32_bf16(ax[m], wi[n][kk], acc[m][n], 0, 0, 0);
                    acc[m][n] = __builtin_amdgcn_mfma_f32_16x16x32_bf16(ah[m], wh[n][kk], acc[m][n], 0, 0, 0);
                }
        }
        __syncthreads();   // B: all Xs/Hs reads done

        *(uint4*)(Xs + r * 256 + ((sg * 16) ^ ((r & 7) << 4))) = xn;   // stage X[t+1]
#pragma unroll
        for (int m = 0; m < 2; ++m)
#pragma unroll
            for (int e = 0; e < 4; ++e) {
                float ig = sigm_fast(acc[m][0][e] + bi);
                float fg = sigm_fast(acc[m][1][e] + bf);
                float gg = tanh_fast(acc[m][2][e] + bg);
                float og = sigm_fast(acc[m][3][e] + bo);
                float cn = fg * c[m][e] + ig * gg;
                c[m][e] = cn;
                float hn = og * tanh_fast(cn);
                int rw = m * 16 + q * 4 + e;
                int byte = rw * 256 + ((((k >> 3) * 16) ^ ((rw & 7) << 4)) | ((k & 7) * 2));
                *(ushort_t*)(Hs + byte) = f2bf(hn);
            }
        __syncthreads();   // C: new h + new Xs visible

        if constexpr (MODE == 0) {
            uint4 v = *(const uint4*)(Hs + r * 256 + ((sg * 16) ^ ((r & 7) << 4)));
            *(uint4*)(Y + ((int64_t)t * 8192 + row0 + r) * 128 + sg * 8) = v;
        }
    }

    if constexpr (MODE == 1) {
        // fused head: thread = (row r, sub sg); cols j = sg*4..sg*4+3
        float accj[4] = {b1[sg * 4 + 0], b1[sg * 4 + 1], b1[sg * 4 + 2], b1[sg * 4 + 3]};
#pragma unroll
        for (int kb = 0; kb < 16; ++kb) {
            uint4 hv = *(const uint4*)(Hs + r * 256 + ((kb * 16) ^ ((r & 7) << 4)));
            const ushort_t* hp = (const ushort_t*)&hv;
#pragma unroll
            for (int j2 = 0; j2 < 8; ++j2) {
                float hval = bf2f(hp[j2]);
                int kx = kb * 8 + j2;
                f32x4 wv = *(const f32x4*)(W1s + kx * 256 + sg * 16);
                accj[0] += hval * wv[0]; accj[1] += hval * wv[1];
                accj[2] += hval * wv[2]; accj[3] += hval * wv[3];
            }
        }
        float s4 = accj[0] + accj[1] + accj[2] + accj[3];
        s4 += __shfl_xor(s4, 1); s4 += __shfl_xor(s4, 2);
        s4 += __shfl_xor(s4, 4); s4 += __shfl_xor(s4, 8);
        float mu = s4 * (1.f / 64.f);
        float d0 = accj[0] - mu, d1 = accj[1] - mu, d2 = accj[2] - mu, d3 = accj[3] - mu;
        float v4 = d0 * d0 + d1 * d1 + d2 * d2 + d3 * d3;
        v4 += __shfl_xor(v4, 1); v4 += __shfl_xor(v4, 2);
        v4 += __shfl_xor(v4, 4); v4 += __shfl_xor(v4, 8);
        float rstd = rsqrtf(v4 * (1.f / 64.f) + EPS);
        float dj[4] = {d0, d1, d2, d3};
        float p = 0.f;
#pragma unroll
        for (int j = 0; j < 4; ++j) {
            int jj = sg * 4 + j;
            float z = fmaxf(dj[j] * rstd * lg[jj] + lb[jj], 0.f);
            p += z * w2[jj];
        }
        p += __shfl_xor(p, 1); p += __shfl_xor(p, 2);
        p += __shfl_xor(p, 4); p += __shfl_xor(p, 8);
        if (sg == 0) out[row0 + r] = p + b2[0];
    }
}

extern "C" void kernel_launch(void* const* d_in, const int* in_sizes, int n_in,
                              void* d_out, int out_size, void* d_ws, size_t ws_size,
                              hipStream_t stream) {
    const float* x    = (const float*)d_in[0];
    const int*   eidx = (const int*)d_in[1];
    const float* ewt  = (const float*)d_in[2];
    const float* efeat= (const float*)d_in[3];
    const float* w_in = (const float*)d_in[4];
    const float* b_in = (const float*)d_in[5];
    const float* lng  = (const float*)d_in[6];
    const float* lnb  = (const float*)d_in[7];
    const float* we1  = (const float*)d_in[8];
    const float* be1  = (const float*)d_in[9];
    const float* we2  = (const float*)d_in[10];
    const float* be2  = (const float*)d_in[11];
    const float* gcnw = (const float*)d_in[12];
    const float* gcnb = (const float*)d_in[13];
    const float* bng  = (const float*)d_in[14];
    const float* bnb  = (const float*)d_in[15];
    const float* wih  = (const float*)d_in[16];
    const float* whh  = (const float*)d_in[17];
    const float* bih  = (const float*)d_in[18];
    const float* bhh  = (const float*)d_in[19];
    const float* wo1  = (const float*)d_in[20];
    const float* bo1  = (const float*)d_in[21];
    const float* lnog = (const float*)d_in[22];
    const float* lnob = (const float*)d_in[23];
    const float* wo2  = (const float*)d_in[24];
    const float* bo2  = (const float*)d_in[25];
    float* out = (float*)d_out;

    // ---- workspace layout (~61MB)
    char* W = (char*)d_ws;
    ushort_t* hA        = (ushort_t*)(W);                        // 4MB  [16][1024][128]
    ushort_t* hB        = (ushort_t*)(W + (4ll << 20));          // 6MB  [23][1024][128]
    ushort_t* y1        = (ushort_t*)(W + (10ll << 20));         // 32MB [16][8192][128]
    ushort_t* hwT       = (ushort_t*)(W + (42ll << 20));         // 4MB  [16][128][1024]
    float*    Apart     = (float*)(W + (46ll << 20));            // 8MB  [16][1024][128]
    float*    Adense    = (float*)(W + (54ll << 20));            // 4MB
    ushort_t* Adense_bf = (ushort_t*)(W + (58ll << 20));         // 2MB
    float*    ew        = (float*)(W + (60ll << 20));            // 128KB
    float*    dis       = (float*)(W + (60ll << 20) + 0x20000);  // 4KB
    float*    bsg       = (float*)(W + (60ll << 20) + 0x21000);  // 4KB [2][512]
    ushort_t* gcnwT     = (ushort_t*)(W + (60ll << 20) + 0x22000); // 128KB
    ushort_t* wgi       = (ushort_t*)(W + (60ll << 20) + 0x42000); // 256KB [2][512][128]
    ushort_t* wgh       = (ushort_t*)(W + (60ll << 20) + 0x82000); // 256KB

    const int* srcI = eidx;
    const int* dstI = eidx + 32768;

    // graph preprocessing
    hipMemsetAsync(dis, 0, 1024 * sizeof(float), stream);
    hipMemsetAsync(Adense, 0, 1048576 * sizeof(float), stream);
    edge_att_deg<<<128, 256, 0, stream>>>(efeat, we1, be1, we2, be2, ewt, dstI, ew, dis);
    make_dis<<<4, 256, 0, stream>>>(dis);
    scatterA<<<128, 256, 0, stream>>>(srcI, dstI, ew, dis, Adense);
    convF2B<<<4096, 256, 0, stream>>>(Adense, Adense_bf, 1048576);
    conv_all<<<772, 256, 0, stream>>>(gcnw, wih, whh, bih, bhh, gcnwT, wgi, wgh, bsg);

    // input projection -> compact hA/hB
    in_proj_ln<<<23552, 128, 0, stream>>>(x, w_in, b_in, lng, lnb, hA, hB);

    // GCN layers on compact state
    for (int l = 0; l < 4; ++l) {
        gemm_feat_t<<<dim3(8, 16, 1), 256, 0, stream>>>(hA, gcnwT + l * 16384, hwT);
        gemm_adj<<<dim3(16, 1, 16), 256, 0, stream>>>(Adense_bf, hwT, Apart);
        gcn_fused<<<312, 256, 0, stream>>>(hA, hB, gcnwT + l * 16384, Apart, dis,
                                           gcnb + l * 128, bng + l * 128, bnb + l * 128);
    }

    // LSTM: layer 1 gathers from compact hA/hB; layer 2 reads y1 and fuses the head
    lstm_layer<0><<<256, 512, 0, stream>>>(hA, hB, nullptr, wgi, wgh, bsg, y1,
                                           nullptr, nullptr, nullptr, nullptr,
                                           nullptr, nullptr, nullptr);
    lstm_layer<1><<<256, 512, 0, stream>>>(nullptr, nullptr, y1,
                                           wgi + 65536, wgh + 65536, bsg + 512, nullptr,
                                           wo1, bo1, lnog, lnob, wo2, bo2, out);
}